// Round 1
// baseline (197.016 us; speedup 1.0000x reference)
//
#include <hip/hip_runtime.h>
#include <hip/hip_bf16.h>
#include <stdint.h>

// MMD loss: L=8192 total rows, D=1024, n=4096 per half.
// result = (Sum_ss + Sum_tt - Sum_cross) / (5 n^2), bandwidth closed-form.

#define L_TOTAL 8192
#define D_FEAT  1024
#define N_HALF  4096
#define TILE    128
#define TTILES  64                      // L/TILE
#define NBLK    (TTILES*(TTILES+1)/2)   // 2080 lower-triangle tiles
#define BK      32

typedef __bf16 bf16_t;
typedef __bf16 bf16x4_t __attribute__((ext_vector_type(4)));
typedef __bf16 bf16x8_t __attribute__((ext_vector_type(8)));
typedef float  f32x4_t  __attribute__((ext_vector_type(4)));

// workspace layout (bytes)
#define XB_OFF   0                              // bf16 X [8192][1024] = 16 MB
#define SQ_OFF   (L_TOTAL * D_FEAT * 2)         // f32 sq[8192]
#define COL_OFF  (SQ_OFF + L_TOTAL * 4)         // f32 colsum[1024]
#define SACC_OFF (COL_OFF + D_FEAT * 4)         // double S_acc
#define C0_OFF   (SACC_OFF + 8)                 // float c0 = log2e/bandwidth

__device__ __forceinline__ void async_ld16(void* lds, const void* g) {
  auto ldsp = (__attribute__((address_space(3))) void*)(uintptr_t)lds;
  auto gp   = (const __attribute__((address_space(1))) void*)(uintptr_t)g;
  __builtin_amdgcn_global_load_lds(gp, ldsp, 16, 0, 0);  // lane i -> base + i*16
}

// --- kernel 1: cast rows to bf16, per-row sum-of-squares (of bf16 values), zero colsum
extern "C" __global__ __launch_bounds__(256) void k_prep(
    const float* __restrict__ src, const float* __restrict__ tgt,
    bf16_t* __restrict__ Xb, float* __restrict__ sq, float* __restrict__ colsum)
{
  const int row = blockIdx.x;
  const int tid = threadIdx.x;
  const float* xr = (row < N_HALF) ? (src + (size_t)row * D_FEAT)
                                   : (tgt + (size_t)(row - N_HALF) * D_FEAT);
  float4 v = ((const float4*)xr)[tid];          // 1024 = 256 threads * 4
  bf16x4_t b;
  b[0] = (bf16_t)v.x; b[1] = (bf16_t)v.y; b[2] = (bf16_t)v.z; b[3] = (bf16_t)v.w;
  float s = 0.f;
  #pragma unroll
  for (int i = 0; i < 4; ++i) { float f = (float)b[i]; s += f * f; }
  *(bf16x4_t*)(Xb + (size_t)row * D_FEAT + tid * 4) = b;

  __shared__ float red[256];
  red[tid] = s;
  __syncthreads();
  for (int off = 128; off > 0; off >>= 1) {
    if (tid < off) red[tid] += red[tid + off];
    __syncthreads();
  }
  if (tid == 0) sq[row] = red[0];
  if (row == 0) {                                 // zeroed before k_colsum runs
    for (int c = tid; c < D_FEAT; c += 256) colsum[c] = 0.f;
  }
}

// --- kernel 2: column sums (for closed-form sum(d2))
extern "C" __global__ __launch_bounds__(256) void k_colsum(
    const float* __restrict__ src, const float* __restrict__ tgt,
    float* __restrict__ colsum)
{
  const int c  = blockIdx.x * 256 + threadIdx.x;  // gridDim.x = 4 -> 1024 cols
  const int r0 = blockIdx.y * 64;                 // gridDim.y = 128
  float s = 0.f;
  for (int r = 0; r < 64; ++r) {
    int row = r0 + r;
    const float* xr = (row < N_HALF) ? (src + (size_t)row * D_FEAT)
                                     : (tgt + (size_t)(row - N_HALF) * D_FEAT);
    s += xr[c];
  }
  atomicAdd(&colsum[c], s);
}

// --- kernel 3: bandwidth = (2L*sum(sq) - 2*||colsum||^2)/(L^2-L)/4 ; zero S_acc
extern "C" __global__ __launch_bounds__(256) void k_bw(
    const float* __restrict__ sq, const float* __restrict__ colsum,
    float* __restrict__ c0out, double* __restrict__ S_acc)
{
  const int tid = threadIdx.x;
  double t = 0.0;
  for (int i = tid; i < L_TOTAL; i += 256) t += (double)sq[i];
  t *= 2.0 * (double)L_TOTAL;
  for (int i = tid; i < D_FEAT; i += 256) { double v = colsum[i]; t -= 2.0 * v * v; }
  __shared__ double red[256];
  red[tid] = t;
  __syncthreads();
  for (int off = 128; off > 0; off >>= 1) {
    if (tid < off) red[tid] += red[tid + off];
    __syncthreads();
  }
  if (tid == 0) {
    double sumd2 = red[0];
    double bw = sumd2 / ((double)L_TOTAL * (double)L_TOTAL - (double)L_TOTAL);
    bw = bw / 4.0;                           // KERNEL_MUL ** (KERNEL_NUM//2)
    *c0out = (float)(1.4426950408889634 / bw);   // log2(e)/bandwidth
    *S_acc = 0.0;
  }
}

// --- kernel 4: fused Gram-MFMA + RBF + signed reduction over lower-triangle tiles
extern "C" __global__ __launch_bounds__(256) void k_mmd(
    const bf16_t* __restrict__ Xb, const float* __restrict__ sq,
    const float* __restrict__ c0ptr, double* __restrict__ S_acc)
{
  __shared__ bf16_t As[TILE * BK];   // [128][32] row-major, 8 KB
  __shared__ bf16_t Bs[TILE * BK];

  const int b = blockIdx.x;
  int ti = (int)((sqrtf(8.f * (float)b + 1.f) - 1.f) * 0.5f);
  while ((ti + 1) * (ti + 2) / 2 <= b) ++ti;
  while (ti * (ti + 1) / 2 > b) --ti;
  const int tj = b - ti * (ti + 1) / 2;          // tj <= ti
  const int row0 = ti * TILE, col0 = tj * TILE;

  const int tid  = threadIdx.x;
  const int lane = tid & 63;
  const int w    = tid >> 6;         // 4 waves, 2x2 over the 128x128 tile
  const int wr   = w >> 1, wc = w & 1;

  f32x4_t acc[4][4] = {};            // wave computes 64x64 = 4x4 frags of 16x16

  // staging geometry: chunk ch = w*2+q covers rows [ch*16, ch*16+16) x BK
  const int srow = lane >> 2;                   // 0..15 within chunk
  const int scol = (lane & 3) * 8;              // bf16 elements along K

  for (int k0 = 0; k0 < D_FEAT; k0 += BK) {
    #pragma unroll
    for (int q = 0; q < 2; ++q) {
      const int ch = w * 2 + q;
      const bf16_t* gA = Xb + (size_t)(row0 + ch * 16 + srow) * D_FEAT + k0 + scol;
      const bf16_t* gB = Xb + (size_t)(col0 + ch * 16 + srow) * D_FEAT + k0 + scol;
      async_ld16(&As[ch * 512], gA);            // wave-uniform LDS base
      async_ld16(&Bs[ch * 512], gB);
    }
    __syncthreads();                 // drains vmcnt -> tiles visible

    bf16x8_t af[4], bfr[4];
    const int kg = (lane >> 4) * 8;  // contiguous-8 K slice (any per-chunk
                                     // bijection cancels between A and B frags)
    #pragma unroll
    for (int m = 0; m < 4; ++m)
      af[m] = *(const bf16x8_t*)&As[(wr * 64 + m * 16 + (lane & 15)) * BK + kg];
    #pragma unroll
    for (int n = 0; n < 4; ++n)
      bfr[n] = *(const bf16x8_t*)&Bs[(wc * 64 + n * 16 + (lane & 15)) * BK + kg];

    #pragma unroll
    for (int m = 0; m < 4; ++m)
      #pragma unroll
      for (int n = 0; n < 4; ++n)
        acc[m][n] = __builtin_amdgcn_mfma_f32_16x16x32_bf16(af[m], bfr[n], acc[m][n], 0, 0, 0);
    __syncthreads();
  }

  // epilogue: d2 -> 5-scale RBF via 1 exp2 + 4 squarings; signed partial sum
  const float c0   = *c0ptr;
  const float sgn  = ((ti < TTILES / 2) == (tj < TTILES / 2)) ? 1.f : -1.f;
  const float wgt  = (ti == tj ? 1.f : 2.f) * sgn;
  float part = 0.f;
  const int colb = col0 + wc * 64 + (lane & 15);
  const int rowb = row0 + wr * 64 + (lane >> 4) * 4;   // C/D map: col=lane&15, row=(lane>>4)*4+reg
  #pragma unroll
  for (int m = 0; m < 4; ++m) {
    #pragma unroll
    for (int n = 0; n < 4; ++n) {
      const float sqj = sq[colb + n * 16];
      #pragma unroll
      for (int r = 0; r < 4; ++r) {
        const float sqi = sq[rowb + m * 16 + r];
        float d2 = sqi + sqj - 2.f * acc[m][n][r];
        d2 = fmaxf(d2, 0.f);
        const float t  = d2 * c0;
        const float e  = __builtin_amdgcn_exp2f(-0.0625f * t); // exp(-d2/(bw*16))
        const float e2 = e * e, e4 = e2 * e2, e8 = e4 * e4, e16 = e8 * e8;
        part += e + e2 + e4 + e8 + e16;
      }
    }
  }
  part *= wgt;

  __shared__ float red[256];
  red[tid] = part;
  __syncthreads();
  for (int off = 128; off > 0; off >>= 1) {
    if (tid < off) red[tid] += red[tid + off];
    __syncthreads();
  }
  if (tid == 0) atomicAdd(S_acc, (double)red[0]);   // double: keeps S error << budget
}

// --- kernel 5: finalize
extern "C" __global__ void k_fin(const double* __restrict__ S_acc, float* __restrict__ out)
{
  out[0] = (float)(*S_acc / (5.0 * (double)N_HALF * (double)N_HALF));
}

extern "C" void kernel_launch(void* const* d_in, const int* in_sizes, int n_in,
                              void* d_out, int out_size, void* d_ws, size_t ws_size,
                              hipStream_t stream) {
  const float* src = (const float*)d_in[0];
  const float* tgt = (const float*)d_in[1];
  float* out = (float*)d_out;
  char* ws = (char*)d_ws;
  bf16_t* Xb     = (bf16_t*)(ws + XB_OFF);
  float*  sq     = (float*)(ws + SQ_OFF);
  float*  colsum = (float*)(ws + COL_OFF);
  double* S_acc  = (double*)(ws + SACC_OFF);
  float*  c0     = (float*)(ws + C0_OFF);

  k_prep  <<<L_TOTAL, 256, 0, stream>>>(src, tgt, Xb, sq, colsum);
  k_colsum<<<dim3(4, 128), 256, 0, stream>>>(src, tgt, colsum);
  k_bw    <<<1, 256, 0, stream>>>(sq, colsum, c0, S_acc);
  k_mmd   <<<NBLK, 256, 0, stream>>>(Xb, sq, c0, S_acc);
  k_fin   <<<1, 1, 0, stream>>>(S_acc, out);
}